// Round 3
// baseline (4457.344 us; speedup 1.0000x reference)
//
#include <hip/hip_runtime.h>
#include <stdint.h>

#define DEVINL __device__ __forceinline__

typedef unsigned short u16;
typedef __attribute__((ext_vector_type(8))) __bf16 bf16x8;
typedef __attribute__((ext_vector_type(4))) float f32x4;

static constexpr int SEQ    = 2048;
static constexpr int DMODEL = 2048;
static constexpr int NHEAD  = 32;
static constexpr int NGRP   = 8;
static constexpr int DHEAD  = 64;
static constexpr int MTOK   = 2 * SEQ;                       // 4096 tokens (B*S)
static constexpr int NQKV   = NHEAD*DHEAD + 2*NGRP*DHEAD;    // 3072

DEVINL u16 f2bf(float f) {                 // f32 -> bf16 RNE
  unsigned u = __builtin_bit_cast(unsigned, f);
  u += 0x7fffu + ((u >> 16) & 1u);
  return (u16)(u >> 16);
}
DEVINL float bf2f(u16 v) {
  unsigned u = (unsigned)v << 16;
  return __builtin_bit_cast(float, u);
}

DEVINL void gld16(const void* g, void* l) {   // global -> LDS direct, 16B/lane
  typedef __attribute__((address_space(1))) const void* gp_t;
  typedef __attribute__((address_space(3))) void* lp_t;
  __builtin_amdgcn_global_load_lds((gp_t)g, (lp_t)l, 16, 0, 0);
}

DEVINL f32x4 mfma16(bf16x8 a, bf16x8 b, f32x4 c) {
  return __builtin_amdgcn_mfma_f32_16x16x32_bf16(a, b, c, 0, 0, 0);
}

// ---------------- x: f32 -> bf16 (vectorized) ----------------
__global__ void k_cvt(const float* __restrict__ s, u16* __restrict__ d) {
  int i = (blockIdx.x * 256 + threadIdx.x) * 4;
  float4 v = *reinterpret_cast<const float4*>(s + i);
  ushort4 o;
  o.x = f2bf(v.x); o.y = f2bf(v.y); o.z = f2bf(v.z); o.w = f2bf(v.w);
  *reinterpret_cast<ushort4*>(d + i) = o;
}

// ---- weights: transpose + cast. dst[n][k] = src[k][n], dst leading dim = DMODEL ----
__global__ void k_tconv(const float* __restrict__ src, u16* __restrict__ dst, int N) {
  __shared__ float t[32][33];
  int n0 = blockIdx.x * 32, k0 = blockIdx.y * 32;
  int tx = threadIdx.x, ty = threadIdx.y;   // 32 x 8
  #pragma unroll
  for (int r = 0; r < 32; r += 8)
    t[r + ty][tx] = src[(size_t)(k0 + r + ty) * N + n0 + tx];
  __syncthreads();
  #pragma unroll
  for (int r = 0; r < 32; r += 8)
    dst[(size_t)(n0 + r + ty) * DMODEL + k0 + tx] = f2bf(t[tx][r + ty]);
}

__global__ void k_packbias(const float* __restrict__ bq, const float* __restrict__ bk,
                           const float* __restrict__ bv, float* __restrict__ d) {
  int i = blockIdx.x * 256 + threadIdx.x;   // 3072 threads
  d[i] = i < 2048 ? bq[i] : (i < 2560 ? bk[i - 2048] : bv[i - 2560]);
}

// ---------------- bf16 GEMM: C[M][ldc] = A[M][K] * Bt[N][K]^T + bias ----------------
// m97-verbatim structure: 128x128 tile, BK=32, 4 waves, global_load_lds(16B),
// LINEAR LDS layout (no swizzle), 2 barriers per K-step.
// F32OUT: store float (final output) vs bf16 (intermediate).
template<int F32OUT>
__global__ __launch_bounds__(256, 3)
void k_gemm(const u16* __restrict__ A, const u16* __restrict__ Bt,
            const float* __restrict__ bias, void* __restrict__ Cv,
            int K, int ldc)
{
  __shared__ __align__(16) u16 lA[128 * 32];
  __shared__ __align__(16) u16 lB[128 * 32];
  const int tid = threadIdx.x;
  const int lane = tid & 63, wid = tid >> 6;
  const int fr = lane & 15, fq = lane >> 4;
  const int n0 = blockIdx.x * 128, m0 = blockIdx.y * 128;
  const int wr = wid >> 1, wc = wid & 1;    // wave's 64x64 output sub-tile

  f32x4 acc[4][4];
  #pragma unroll
  for (int i = 0; i < 4; ++i)
    #pragma unroll
    for (int j = 0; j < 4; ++j) acc[i][j] = f32x4{0.f, 0.f, 0.f, 0.f};

  // staging: 512 16B-slots per tile; wave issues 2; slot s -> LDS byte s*16,
  // source row = s>>2, k-slot = s&3 (linear)
  const int s0 = (wid * 2 + 0) * 64 + lane;
  const int s1 = (wid * 2 + 1) * 64 + lane;
  const int r0 = s0 >> 2, k0s = 8 * (s0 & 3);
  const int r1 = s1 >> 2, k1s = 8 * (s1 & 3);
  const u16* gA0 = A  + (size_t)(m0 + r0) * K + k0s;
  const u16* gA1 = A  + (size_t)(m0 + r1) * K + k1s;
  const u16* gB0 = Bt + (size_t)(n0 + r0) * K + k0s;
  const u16* gB1 = Bt + (size_t)(n0 + r1) * K + k1s;
  u16* lA0 = &lA[(wid * 2 + 0) * 512];
  u16* lA1 = &lA[(wid * 2 + 1) * 512];
  u16* lB0 = &lB[(wid * 2 + 0) * 512];
  u16* lB1 = &lB[(wid * 2 + 1) * 512];

  int aoff[4], boff[4];                     // linear ds_read byte offsets
  #pragma unroll
  for (int i = 0; i < 4; ++i) {
    aoff[i] = (wr * 64 + i * 16 + fr) * 64 + fq * 16;
    boff[i] = (wc * 64 + i * 16 + fr) * 64 + fq * 16;
  }
  const char* laB = (const char*)lA;
  const char* lbB = (const char*)lB;

  for (int kt = 0; kt < K; kt += 32) {
    gld16(gA0, lA0); gld16(gA1, lA1);
    gld16(gB0, lB0); gld16(gB1, lB1);
    gA0 += 32; gA1 += 32; gB0 += 32; gB1 += 32;
    __syncthreads();                         // drains vmcnt -> tiles visible
    bf16x8 a[4], b[4];
    #pragma unroll
    for (int i = 0; i < 4; ++i) a[i] = *(const bf16x8*)(laB + aoff[i]);
    #pragma unroll
    for (int j = 0; j < 4; ++j) b[j] = *(const bf16x8*)(lbB + boff[j]);
    #pragma unroll
    for (int i = 0; i < 4; ++i)
      #pragma unroll
      for (int j = 0; j < 4; ++j)
        acc[i][j] = mfma16(a[i], b[j], acc[i][j]);
    __syncthreads();                         // before next overwrite
  }

  // epilogue: C/D layout col = lane&15, row = (lane>>4)*4 + t  [verified m89/m91]
  #pragma unroll
  for (int i = 0; i < 4; ++i) {
    const int row = m0 + wr * 64 + i * 16 + fq * 4;
    #pragma unroll
    for (int j = 0; j < 4; ++j) {
      const int col = n0 + wc * 64 + j * 16 + fr;
      const float bvl = bias[col];
      #pragma unroll
      for (int t = 0; t < 4; ++t) {
        const float val = acc[i][j][t] + bvl;
        if (F32OUT)
          ((float*)Cv)[(size_t)(row + t) * ldc + col] = val;
        else
          ((u16*)Cv)[(size_t)(row + t) * ldc + col] = f2bf(val);
      }
    }
  }
}

// ---------------- simple vector flash attention (correctness baseline) ----------------
// 1 wave = 1 (b,h,q-row). lane = kk*16+dd: 4 key-groups (kk) x 16 d-slices (dd),
// each lane covers d = 4*dd..4*dd+3. Per 4-key step, group kk handles key t0+kk:
// dot over d via 4-step shfl reduce within the 16-lane group; per-group online
// softmax state (m,l,acc[4]); final split-softmax merge across groups (xor 16,32).
__global__ __launch_bounds__(256, 4)
void k_attn_simple(const u16* __restrict__ qkv, u16* __restrict__ ctx) {
  const int lane = threadIdx.x & 63, wid = threadIdx.x >> 6;
  const int kk = lane >> 4, dd = lane & 15;
  const int blk = blockIdx.x;               // 32768 = 2 * 32 * 512
  const int qr4 = blk & 511;
  const int h   = (blk >> 9) & 31;
  const int bb  = blk >> 14;
  const int g   = h >> 2;                   // GS = 4
  const int qrow = qr4 * 4 + wid;
  const size_t tokbase = (size_t)bb * SEQ;

  const u16* qp = qkv + (tokbase + qrow) * NQKV + h * 64 + 4 * dd;
  ushort4 qv = *reinterpret_cast<const ushort4*>(qp);
  const float q0 = bf2f(qv.x), q1 = bf2f(qv.y), q2 = bf2f(qv.z), q3 = bf2f(qv.w);

  const u16* kp = qkv + tokbase * NQKV + 2048 + g * 64 + 4 * dd;
  const u16* vp = kp + 512;
  float m = -1e30f, l = 0.f;
  float a0 = 0.f, a1 = 0.f, a2 = 0.f, a3 = 0.f;
  const float cs = 0.18033688011112042f;    // log2(e) / sqrt(64)

  for (int t0 = 0; t0 < SEQ; t0 += 4) {
    const size_t roff = (size_t)(t0 + kk) * NQKV;
    ushort4 kv = *reinterpret_cast<const ushort4*>(kp + roff);
    float s = bf2f(kv.x)*q0 + bf2f(kv.y)*q1 + bf2f(kv.z)*q2 + bf2f(kv.w)*q3;
    s += __shfl_xor(s, 1); s += __shfl_xor(s, 2);
    s += __shfl_xor(s, 4); s += __shfl_xor(s, 8);
    const float mn = fmaxf(m, s);
    const float r_ = exp2f((m - mn) * cs);
    const float p  = exp2f((s - mn) * cs);
    l = l * r_ + p; m = mn;
    ushort4 vv = *reinterpret_cast<const ushort4*>(vp + roff);
    a0 = a0 * r_ + p * bf2f(vv.x);
    a1 = a1 * r_ + p * bf2f(vv.y);
    a2 = a2 * r_ + p * bf2f(vv.z);
    a3 = a3 * r_ + p * bf2f(vv.w);
  }
  // merge the 4 kk-groups (split softmax)
  #pragma unroll
  for (int off = 16; off <= 32; off <<= 1) {
    const float mo = __shfl_xor(m, off);
    const float lo = __shfl_xor(l, off);
    const float b0 = __shfl_xor(a0, off);
    const float b1 = __shfl_xor(a1, off);
    const float b2 = __shfl_xor(a2, off);
    const float b3 = __shfl_xor(a3, off);
    const float mn = fmaxf(m, mo);
    const float w1 = exp2f((m - mn) * cs);
    const float w2 = exp2f((mo - mn) * cs);
    l = l * w1 + lo * w2;
    a0 = a0 * w1 + b0 * w2;
    a1 = a1 * w1 + b1 * w2;
    a2 = a2 * w1 + b2 * w2;
    a3 = a3 * w1 + b3 * w2;
    m = mn;
  }
  if (kk == 0) {
    const float inv = 1.0f / l;
    ushort4 o;
    o.x = f2bf(a0 * inv); o.y = f2bf(a1 * inv);
    o.z = f2bf(a2 * inv); o.w = f2bf(a3 * inv);
    *reinterpret_cast<ushort4*>(ctx + (tokbase + qrow) * DMODEL + h * 64 + 4 * dd) = o;
  }
}

extern "C" void kernel_launch(void* const* d_in, const int* in_sizes, int n_in,
                              void* d_out, int out_size, void* d_ws, size_t ws_size,
                              hipStream_t stream) {
  const float* x  = (const float*)d_in[0];
  const float* Wq = (const float*)d_in[1];
  const float* bq = (const float*)d_in[2];
  const float* Wk = (const float*)d_in[3];
  const float* bk = (const float*)d_in[4];
  const float* Wv = (const float*)d_in[5];
  const float* bv = (const float*)d_in[6];
  const float* Wo = (const float*)d_in[7];
  const float* bo = (const float*)d_in[8];

  char* ws = (char*)d_ws;
  size_t off = 0;
  auto take = [&](size_t bytes) { char* p = ws + off; off += (bytes + 255) & ~(size_t)255; return p; };
  u16*   xb    = (u16*)  take((size_t)MTOK * DMODEL * 2);   // x bf16; REUSED as ctx after gemm1
  u16*   wqkvT = (u16*)  take((size_t)NQKV * DMODEL * 2);   // [Wq;Wk;Wv] transposed
  u16*   woT   = (u16*)  take((size_t)DMODEL * DMODEL * 2); // Wo transposed
  u16*   qkv   = (u16*)  take((size_t)MTOK * NQKV * 2);     // projections (Q,K,V)
  float* bqkv  = (float*)take((size_t)NQKV * 4);            // packed qkv bias

  // ws overflow guard: if scratch too small, emit zeros (signature: absmax == max|ref|)
  if (off > ws_size) {
    hipMemsetAsync(d_out, 0, (size_t)out_size * 4, stream);
    return;
  }

  dim3 tb(32, 8);
  k_cvt<<<(MTOK * DMODEL) / (4 * 256), 256, 0, stream>>>(x, xb);
  k_tconv<<<dim3(64, 64), tb, 0, stream>>>(Wq, wqkvT, 2048);
  k_tconv<<<dim3(16, 64), tb, 0, stream>>>(Wk, wqkvT + (size_t)2048 * DMODEL, 512);
  k_tconv<<<dim3(16, 64), tb, 0, stream>>>(Wv, wqkvT + (size_t)2560 * DMODEL, 512);
  k_tconv<<<dim3(64, 64), tb, 0, stream>>>(Wo, woT, 2048);
  k_packbias<<<NQKV / 256, 256, 0, stream>>>(bq, bk, bv, bqkv);

  // QKV projection: M=4096, N=3072, K=2048 (bf16 out)
  k_gemm<0><<<dim3(NQKV / 128, MTOK / 128), 256, 0, stream>>>(
      xb, wqkvT, bqkv, qkv, DMODEL, NQKV);

  // attention: 1 wave per (b,h,q-row); ctx written into xb (gemm1 done with it)
  u16* ctxb = xb;
  k_attn_simple<<<32768, 256, 0, stream>>>(qkv, ctxb);

  // output projection: M=4096, N=2048, K=2048 -> d_out (FLOAT32)
  k_gemm<1><<<dim3(DMODEL / 128, MTOK / 128), 256, 0, stream>>>(
      ctxb, woT, bo, d_out, DMODEL, DMODEL);
}

// Round 4
// 585.543 us; speedup vs baseline: 7.6123x; 7.6123x over previous
//
#include <hip/hip_runtime.h>
#include <stdint.h>

#define DEVINL __device__ __forceinline__

typedef unsigned short u16;
typedef __attribute__((ext_vector_type(8))) __bf16 bf16x8;
typedef __attribute__((ext_vector_type(4))) float f32x4;

static constexpr int SEQ    = 2048;
static constexpr int DMODEL = 2048;
static constexpr int NHEAD  = 32;
static constexpr int NGRP   = 8;
static constexpr int DHEAD  = 64;
static constexpr int MTOK   = 2 * SEQ;                       // 4096 tokens (B*S)
static constexpr int NQKV   = NHEAD*DHEAD + 2*NGRP*DHEAD;    // 3072

DEVINL u16 f2bf(float f) {                 // f32 -> bf16 RNE
  unsigned u = __builtin_bit_cast(unsigned, f);
  u += 0x7fffu + ((u >> 16) & 1u);
  return (u16)(u >> 16);
}
DEVINL float bf2f(u16 v) {
  unsigned u = (unsigned)v << 16;
  return __builtin_bit_cast(float, u);
}

DEVINL void gld16(const void* g, void* l) {   // global -> LDS direct, 16B/lane
  typedef __attribute__((address_space(1))) const void* gp_t;
  typedef __attribute__((address_space(3))) void* lp_t;
  __builtin_amdgcn_global_load_lds((gp_t)g, (lp_t)l, 16, 0, 0);
}

DEVINL f32x4 mfma16(bf16x8 a, bf16x8 b, f32x4 c) {
  return __builtin_amdgcn_mfma_f32_16x16x32_bf16(a, b, c, 0, 0, 0);
}

// ---------------- x: f32 -> bf16 (vectorized) ----------------
__global__ void k_cvt(const float* __restrict__ s, u16* __restrict__ d) {
  int i = (blockIdx.x * 256 + threadIdx.x) * 4;
  float4 v = *reinterpret_cast<const float4*>(s + i);
  ushort4 o;
  o.x = f2bf(v.x); o.y = f2bf(v.y); o.z = f2bf(v.z); o.w = f2bf(v.w);
  *reinterpret_cast<ushort4*>(d + i) = o;
}

// ---- weights: transpose + cast. dst[n][k] = src[k][n], dst leading dim = DMODEL ----
__global__ void k_tconv(const float* __restrict__ src, u16* __restrict__ dst, int N) {
  __shared__ float t[32][33];
  int n0 = blockIdx.x * 32, k0 = blockIdx.y * 32;
  int tx = threadIdx.x, ty = threadIdx.y;   // 32 x 8
  #pragma unroll
  for (int r = 0; r < 32; r += 8)
    t[r + ty][tx] = src[(size_t)(k0 + r + ty) * N + n0 + tx];
  __syncthreads();
  #pragma unroll
  for (int r = 0; r < 32; r += 8)
    dst[(size_t)(n0 + r + ty) * DMODEL + k0 + tx] = f2bf(t[tx][r + ty]);
}

__global__ void k_packbias(const float* __restrict__ bq, const float* __restrict__ bk,
                           const float* __restrict__ bv, float* __restrict__ d) {
  int i = blockIdx.x * 256 + threadIdx.x;   // 3072 threads
  d[i] = i < 2048 ? bq[i] : (i < 2560 ? bk[i - 2048] : bv[i - 2560]);
}

// ---- V transpose: vT[((b*8+g)*64 + d)][s] = qkv[(b*2048+s)*NQKV + 2560 + g*64 + d] ----
__global__ void k_vt(const u16* __restrict__ qkv, u16* __restrict__ vT) {
  __shared__ u16 t[64][65];
  const int blk = blockIdx.x;        // b*256 + g*32 + st   (2*8*32 = 512)
  const int st = blk & 31, g = (blk >> 5) & 7, bb = blk >> 8;
  const int s0 = st * 64;
  const int tx = threadIdx.x & 63, ty = threadIdx.x >> 6;  // 64 x 4
  #pragma unroll
  for (int r = 0; r < 64; r += 4)
    t[r + ty][tx] = qkv[((size_t)bb * 2048 + s0 + r + ty) * NQKV + 2560 + g * 64 + tx];
  __syncthreads();
  #pragma unroll
  for (int r = 0; r < 64; r += 4)
    vT[((size_t)((bb * 8 + g) * 64) + r + ty) * SEQ + s0 + tx] = t[tx][r + ty];
}

// ---------------- bf16 GEMM: C[M][ldc] = A[M][K] * Bt[N][K]^T + bias ----------------
// m97-verbatim structure: 128x128 tile, BK=32, 4 waves, global_load_lds(16B),
// LINEAR LDS layout (no swizzle), 2 barriers per K-step.
// F32OUT: store float (final output) vs bf16 (intermediate).
template<int F32OUT>
__global__ __launch_bounds__(256, 3)
void k_gemm(const u16* __restrict__ A, const u16* __restrict__ Bt,
            const float* __restrict__ bias, void* __restrict__ Cv,
            int K, int ldc)
{
  __shared__ __align__(16) u16 lA[128 * 32];
  __shared__ __align__(16) u16 lB[128 * 32];
  const int tid = threadIdx.x;
  const int lane = tid & 63, wid = tid >> 6;
  const int fr = lane & 15, fq = lane >> 4;
  const int n0 = blockIdx.x * 128, m0 = blockIdx.y * 128;
  const int wr = wid >> 1, wc = wid & 1;    // wave's 64x64 output sub-tile

  f32x4 acc[4][4];
  #pragma unroll
  for (int i = 0; i < 4; ++i)
    #pragma unroll
    for (int j = 0; j < 4; ++j) acc[i][j] = f32x4{0.f, 0.f, 0.f, 0.f};

  const int s0 = (wid * 2 + 0) * 64 + lane;
  const int s1 = (wid * 2 + 1) * 64 + lane;
  const int r0 = s0 >> 2, k0s = 8 * (s0 & 3);
  const int r1 = s1 >> 2, k1s = 8 * (s1 & 3);
  const u16* gA0 = A  + (size_t)(m0 + r0) * K + k0s;
  const u16* gA1 = A  + (size_t)(m0 + r1) * K + k1s;
  const u16* gB0 = Bt + (size_t)(n0 + r0) * K + k0s;
  const u16* gB1 = Bt + (size_t)(n0 + r1) * K + k1s;
  u16* lA0 = &lA[(wid * 2 + 0) * 512];
  u16* lA1 = &lA[(wid * 2 + 1) * 512];
  u16* lB0 = &lB[(wid * 2 + 0) * 512];
  u16* lB1 = &lB[(wid * 2 + 1) * 512];

  int aoff[4], boff[4];                     // linear ds_read byte offsets
  #pragma unroll
  for (int i = 0; i < 4; ++i) {
    aoff[i] = (wr * 64 + i * 16 + fr) * 64 + fq * 16;
    boff[i] = (wc * 64 + i * 16 + fr) * 64 + fq * 16;
  }
  const char* laB = (const char*)lA;
  const char* lbB = (const char*)lB;

  for (int kt = 0; kt < K; kt += 32) {
    gld16(gA0, lA0); gld16(gA1, lA1);
    gld16(gB0, lB0); gld16(gB1, lB1);
    gA0 += 32; gA1 += 32; gB0 += 32; gB1 += 32;
    __syncthreads();                         // drains vmcnt -> tiles visible
    bf16x8 a[4], b[4];
    #pragma unroll
    for (int i = 0; i < 4; ++i) a[i] = *(const bf16x8*)(laB + aoff[i]);
    #pragma unroll
    for (int j = 0; j < 4; ++j) b[j] = *(const bf16x8*)(lbB + boff[j]);
    #pragma unroll
    for (int i = 0; i < 4; ++i)
      #pragma unroll
      for (int j = 0; j < 4; ++j)
        acc[i][j] = mfma16(a[i], b[j], acc[i][j]);
    __syncthreads();                         // before next overwrite
  }

  // epilogue: C/D layout col = lane&15, row = (lane>>4)*4 + t  [verified m89/m91]
  #pragma unroll
  for (int i = 0; i < 4; ++i) {
    const int row = m0 + wr * 64 + i * 16 + fq * 4;
    #pragma unroll
    for (int j = 0; j < 4; ++j) {
      const int col = n0 + wc * 64 + j * 16 + fr;
      const float bvl = bias[col];
      #pragma unroll
      for (int t = 0; t < 4; ++t) {
        const float val = acc[i][j][t] + bvl;
        if (F32OUT)
          ((float*)Cv)[(size_t)(row + t) * ldc + col] = val;
        else
          ((u16*)Cv)[(size_t)(row + t) * ldc + col] = f2bf(val);
      }
    }
  }
}

// ---------------- MFMA flash attention ----------------
// 1 wave = 16 q-rows of one (b,h); KV tile = 64; K/V frags straight from global
// (per-(b,g) K+V = 512 KB, L2 resident, reused by 512 waves). P goes through a
// per-wave XOR-swizzled LDS buffer to convert C-layout -> A-layout. No cross-wave sync.
__global__ __launch_bounds__(256, 3)
void k_attn(const u16* __restrict__ qkv, const u16* __restrict__ vT,
            u16* __restrict__ ctx)
{
  __shared__ __align__(16) u16 pls[4][1024];     // per-wave 16x64 bf16, XOR-swizzled
  const int tid = threadIdx.x, lane = tid & 63, wid = tid >> 6;
  const int fr = lane & 15, fq = lane >> 4;
  const int h = blockIdx.y, bb = blockIdx.z, g = h >> 2;   // GS = 4
  const int q0 = blockIdx.x * 64 + wid * 16;
  const size_t tokbase = (size_t)bb * SEQ;

  bf16x8 aq[2];                                  // Q A-frags (16 rows x 64 d)
  {
    const u16* qp = qkv + (tokbase + q0 + fr) * NQKV + h * 64 + fq * 8;
    aq[0] = *(const bf16x8*)qp;
    aq[1] = *(const bf16x8*)(qp + 32);
  }
  f32x4 ao[4];
  #pragma unroll
  for (int j = 0; j < 4; ++j) ao[j] = f32x4{0.f, 0.f, 0.f, 0.f};
  float mrow[4] = {-1e30f, -1e30f, -1e30f, -1e30f};
  float lrow[4] = {0.f, 0.f, 0.f, 0.f};

  const u16* kbase = qkv + tokbase * NQKV + 2048 + g * 64;
  const u16* vbase = vT + (size_t)(bb * 8 + g) * 64 * SEQ;
  char* myp = (char*)&pls[wid][0];
  const float cs = 0.18033688011112042f;         // log2(e) / sqrt(64)

  for (int tk = 0; tk < SEQ; tk += 64) {
    // S = Q K^T  (raw scores; scale folded into exp2 constant)
    f32x4 as[4];
    #pragma unroll
    for (int j = 0; j < 4; ++j) as[j] = f32x4{0.f, 0.f, 0.f, 0.f};
    #pragma unroll
    for (int ks = 0; ks < 2; ++ks) {
      #pragma unroll
      for (int j = 0; j < 4; ++j) {
        bf16x8 bk = *(const bf16x8*)(kbase + (size_t)(tk + j * 16 + fr) * NQKV + ks * 32 + fq * 8);
        as[j] = mfma16(aq[ks], bk, as[j]);
      }
    }
    // online softmax: q-row = fq*4 + t (C-layout rows), key = j*16 + fr
    float rescale[4], sum[4];
    #pragma unroll
    for (int t = 0; t < 4; ++t) {
      float mx = fmaxf(fmaxf(as[0][t], as[1][t]), fmaxf(as[2][t], as[3][t]));
      #pragma unroll
      for (int off = 1; off < 16; off <<= 1) mx = fmaxf(mx, __shfl_xor(mx, off));
      float mn = fmaxf(mrow[t], mx);
      rescale[t] = exp2f((mrow[t] - mn) * cs);
      mrow[t] = mn;
      sum[t] = 0.f;
    }
    #pragma unroll
    for (int j = 0; j < 4; ++j) {
      #pragma unroll
      for (int t = 0; t < 4; ++t) {
        float p = exp2f((as[j][t] - mrow[t]) * cs);
        sum[t] += p;
        int prow = fq * 4 + t, pcol = j * 16 + fr;
        *(u16*)(myp + ((prow * 128 + pcol * 2) ^ ((prow & 7) << 4))) = f2bf(p);
      }
    }
    #pragma unroll
    for (int t = 0; t < 4; ++t) {
      float s = sum[t];
      #pragma unroll
      for (int off = 1; off < 16; off <<= 1) s += __shfl_xor(s, off);
      lrow[t] = lrow[t] * rescale[t] + s;
    }
    #pragma unroll
    for (int j = 0; j < 4; ++j)
      #pragma unroll
      for (int t = 0; t < 4; ++t) ao[j][t] *= rescale[t];

    asm volatile("s_waitcnt lgkmcnt(0)" ::: "memory");  // P writes -> P reads (same wave)

    // O += P V : A-frag from LDS (swizzled), B-frag from vT (s-contiguous)
    #pragma unroll
    for (int ks = 0; ks < 2; ++ks) {
      bf16x8 pa = *(const bf16x8*)(myp + ((fr * 128 + ks * 64 + fq * 16) ^ ((fr & 7) << 4)));
      #pragma unroll
      for (int j = 0; j < 4; ++j) {
        bf16x8 bv = *(const bf16x8*)(vbase + (size_t)(j * 16 + fr) * SEQ + tk + ks * 32 + fq * 8);
        ao[j] = mfma16(pa, bv, ao[j]);
      }
    }
  }
  // normalize + store ctx [token][h*64 + d]
  #pragma unroll
  for (int t = 0; t < 4; ++t) {
    const int qrow = q0 + fq * 4 + t;
    const float inv = 1.0f / lrow[t];
    #pragma unroll
    for (int j = 0; j < 4; ++j)
      ctx[(tokbase + qrow) * DMODEL + h * 64 + j * 16 + fr] = f2bf(ao[j][t] * inv);
  }
}

extern "C" void kernel_launch(void* const* d_in, const int* in_sizes, int n_in,
                              void* d_out, int out_size, void* d_ws, size_t ws_size,
                              hipStream_t stream) {
  const float* x  = (const float*)d_in[0];
  const float* Wq = (const float*)d_in[1];
  const float* bq = (const float*)d_in[2];
  const float* Wk = (const float*)d_in[3];
  const float* bk = (const float*)d_in[4];
  const float* Wv = (const float*)d_in[5];
  const float* bv = (const float*)d_in[6];
  const float* Wo = (const float*)d_in[7];
  const float* bo = (const float*)d_in[8];

  char* ws = (char*)d_ws;
  size_t off = 0;
  auto take = [&](size_t bytes) { char* p = ws + off; off += (bytes + 255) & ~(size_t)255; return p; };
  u16*   xb    = (u16*)  take((size_t)MTOK * DMODEL * 2);   // x bf16; REUSED as ctx after gemm1
  u16*   wqkvT = (u16*)  take((size_t)NQKV * DMODEL * 2);   // [Wq;Wk;Wv] transposed
  u16*   woT   = (u16*)  take((size_t)DMODEL * DMODEL * 2); // Wo transposed
  u16*   qkv   = (u16*)  take((size_t)MTOK * NQKV * 2);     // projections (Q,K,V)
  u16*   vTb   = (u16*)  take((size_t)2 * NGRP * DHEAD * SEQ * 2); // V^T [b,g,d,s]
  float* bqkv  = (float*)take((size_t)NQKV * 4);            // packed qkv bias

  // ws overflow guard: if scratch too small, emit zeros (signature: absmax == max|ref|)
  if (off > ws_size) {
    hipMemsetAsync(d_out, 0, (size_t)out_size * 4, stream);
    return;
  }

  dim3 tb(32, 8);
  k_cvt<<<(MTOK * DMODEL) / (4 * 256), 256, 0, stream>>>(x, xb);
  k_tconv<<<dim3(64, 64), tb, 0, stream>>>(Wq, wqkvT, 2048);
  k_tconv<<<dim3(16, 64), tb, 0, stream>>>(Wk, wqkvT + (size_t)2048 * DMODEL, 512);
  k_tconv<<<dim3(16, 64), tb, 0, stream>>>(Wv, wqkvT + (size_t)2560 * DMODEL, 512);
  k_tconv<<<dim3(64, 64), tb, 0, stream>>>(Wo, woT, 2048);
  k_packbias<<<NQKV / 256, 256, 0, stream>>>(bq, bk, bv, bqkv);

  // QKV projection: M=4096, N=3072, K=2048 (bf16 out)
  k_gemm<0><<<dim3(NQKV / 128, MTOK / 128), 256, 0, stream>>>(
      xb, wqkvT, bqkv, qkv, DMODEL, NQKV);

  // V transpose for the PV step's B-operand
  k_vt<<<512, 256, 0, stream>>>(qkv, vTb);

  // MFMA flash attention: grid = (q-tiles, heads, batch); ctx into xb
  u16* ctxb = xb;
  k_attn<<<dim3(SEQ / 64, NHEAD, 2), 256, 0, stream>>>(qkv, vTb, ctxb);

  // output projection: M=4096, N=2048, K=2048 -> d_out (FLOAT32)
  k_gemm<1><<<dim3(DMODEL / 128, MTOK / 128), 256, 0, stream>>>(
      ctxb, woT, bo, d_out, DMODEL, DMODEL);
}